// Round 2
// baseline (1151.237 us; speedup 1.0000x reference)
//
#include <hip/hip_runtime.h>
#include <hip/hip_bf16.h>

#define NN 100000
#define EE 800000
#define DFEAT 128
#define DCLS 40
#define THRV 0.1f
#define EPSV 1e-8f

// ---------------- utility kernels ----------------

__global__ void set_ones_k(float* __restrict__ p, int n) {
    int i = blockIdx.x * blockDim.x + threadIdx.x;
    if (i < n) p[i] = 1.0f;
}

__global__ void rsqrt_k(float* __restrict__ p, int n) {
    int i = blockIdx.x * blockDim.x + threadIdx.x;
    if (i < n) p[i] = rsqrtf(p[i]);
}

// ---------------- row norms: one wave per node, D=128 ----------------

__global__ void row_norm_k(const float* __restrict__ x, float* __restrict__ norms, int n) {
    int node = blockIdx.x * 4 + (threadIdx.x >> 6);
    int lane = threadIdx.x & 63;
    if (node >= n) return;
    float2 v = reinterpret_cast<const float2*>(x)[(size_t)node * 64 + lane];
    float ss = v.x * v.x + v.y * v.y;
    #pragma unroll
    for (int off = 32; off; off >>= 1) ss += __shfl_xor(ss, off);
    if (lane == 0) norms[node] = fmaxf(sqrtf(ss), EPSV);
}

// ---------------- per-edge cosine sim: one wave per edge ----------------
// SECOND pass: alive = (ew_prev != 0); overwrites ew in place.
// Always accumulates alive ew into deg[row] (deg pre-set to 1.0 for self loop).

template<bool SECOND>
__global__ void edge_sim_k(const float* __restrict__ x, const float* __restrict__ norms,
                           const int* __restrict__ rows, const int* __restrict__ cols,
                           float* __restrict__ ew, float* __restrict__ deg, int ne) {
    int e = blockIdx.x * 4 + (threadIdx.x >> 6);
    int lane = threadIdx.x & 63;
    if (e >= ne) return;
    if (SECOND) {
        float prev = ew[e];
        if (prev == 0.0f) return;  // ew stays 0
    }
    int r = rows[e], c = cols[e];
    const float2* xr = reinterpret_cast<const float2*>(x) + (size_t)r * 64;
    const float2* xc = reinterpret_cast<const float2*>(x) + (size_t)c * 64;
    float2 a = xr[lane], b = xc[lane];
    float d = a.x * b.x + a.y * b.y;
    #pragma unroll
    for (int off = 32; off; off >>= 1) d += __shfl_xor(d, off);
    if (lane == 0) {
        float s = d / (norms[r] * norms[c]);
        float w = (s >= THRV) ? s : 0.0f;
        ew[e] = w;
        if (w != 0.0f) atomicAdd(&deg[r], w);
    }
}

// ---------------- GEMM: [n,128] x [128,128] -> [n,128] ----------------
// 32 rows/block; K tiled by 64. Each thread: 4 rows x 4 cols.

__global__ __launch_bounds__(256) void gemm_nh_k(const float* __restrict__ A,
                                                 const float* __restrict__ W,
                                                 float* __restrict__ C, int n) {
    __shared__ float Ws[64 * 128];   // 32 KB
    __shared__ float Xs[32 * 64];    // 8 KB
    int tid = threadIdx.x;
    int row0 = blockIdx.x * 32;
    int cg = tid & 31;   // col group (4 cols)
    int rl = tid >> 5;   // 0..7
    float4 acc[4];
    #pragma unroll
    for (int i = 0; i < 4; i++) acc[i] = make_float4(0.f, 0.f, 0.f, 0.f);

    for (int kt = 0; kt < 2; kt++) {
        const float4* Wg = reinterpret_cast<const float4*>(W + kt * 64 * 128);
        float4* Ws4 = reinterpret_cast<float4*>(Ws);
        #pragma unroll
        for (int i = 0; i < 8; i++) Ws4[tid + 256 * i] = Wg[tid + 256 * i];
        float4* Xs4 = reinterpret_cast<float4*>(Xs);
        #pragma unroll
        for (int i = 0; i < 2; i++) {
            int idx = tid + 256 * i;          // 0..511
            int rr = idx >> 4, kq = idx & 15;
            int grow = row0 + rr; if (grow >= n) grow = n - 1;
            Xs4[idx] = reinterpret_cast<const float4*>(A + (size_t)grow * 128 + kt * 64)[kq];
        }
        __syncthreads();
        for (int k = 0; k < 64; k++) {
            float4 wv = reinterpret_cast<const float4*>(Ws + k * 128)[cg];
            #pragma unroll
            for (int r4 = 0; r4 < 4; r4++) {
                float xv = Xs[(rl + 8 * r4) * 64 + k];
                acc[r4].x += xv * wv.x; acc[r4].y += xv * wv.y;
                acc[r4].z += xv * wv.z; acc[r4].w += xv * wv.w;
            }
        }
        __syncthreads();
    }
    #pragma unroll
    for (int r4 = 0; r4 < 4; r4++) {
        int grow = row0 + rl + 8 * r4;
        if (grow < n) reinterpret_cast<float4*>(C + (size_t)grow * 128)[cg] = acc[r4];
    }
}

// ---------------- GEMM: [n,128] x [128,40] -> [n,40] ----------------
// 64 rows/block. Each thread: 2 rows x 5 cols.

__global__ __launch_bounds__(256) void gemm_nc_k(const float* __restrict__ A,
                                                 const float* __restrict__ W,
                                                 float* __restrict__ C, int n) {
    __shared__ float Ws[128 * 40];     // 20 KB
    __shared__ float Xs[64 * 130];     // padded stride 130, ~33.3 KB
    int tid = threadIdx.x;
    int row0 = blockIdx.x * 64;
    for (int i = tid; i < 128 * 40; i += 256) Ws[i] = W[i];
    #pragma unroll
    for (int i = 0; i < 8; i++) {
        int idx = tid + 256 * i;          // 0..2047
        int rr = idx >> 5, kq = idx & 31;
        int grow = row0 + rr; if (grow >= n) grow = n - 1;
        float4 v = reinterpret_cast<const float4*>(A + (size_t)grow * 128)[kq];
        float* dst = &Xs[rr * 130 + kq * 4];
        dst[0] = v.x; dst[1] = v.y; dst[2] = v.z; dst[3] = v.w;
    }
    __syncthreads();
    int c5 = tid & 7;    // cols 5*c5 .. +4
    int r  = tid >> 3;   // 0..31 -> rows r, r+32
    float acc0[5] = {0, 0, 0, 0, 0}, acc1[5] = {0, 0, 0, 0, 0};
    for (int k = 0; k < 128; k++) {
        float x0 = Xs[r * 130 + k], x1 = Xs[(r + 32) * 130 + k];
        #pragma unroll
        for (int c = 0; c < 5; c++) {
            float wv = Ws[k * 40 + c5 * 5 + c];
            acc0[c] += x0 * wv; acc1[c] += x1 * wv;
        }
    }
    int g0 = row0 + r, g1 = row0 + r + 32;
    if (g0 < n) {
        for (int c = 0; c < 5; c++) C[(size_t)g0 * 40 + c5 * 5 + c] = acc0[c];
    }
    if (g1 < n) {
        for (int c = 0; c < 5; c++) C[(size_t)g1 * 40 + c5 * 5 + c] = acc1[c];
    }
}

// ---------------- edge aggregation: thread per (edge, feature) ----------------

template<int D>
__global__ void aggregate_k(const float* __restrict__ h, const int* __restrict__ rows,
                            const int* __restrict__ cols, const float* __restrict__ ew,
                            const float* __restrict__ dinv, float* __restrict__ agg, int ne) {
    int gid = blockIdx.x * blockDim.x + threadIdx.x;
    int e = gid / D;
    int f = gid - e * D;
    if (e >= ne) return;
    float w = ew[e];
    if (w == 0.0f) return;
    int r = rows[e], c = cols[e];
    float nv = dinv[r] * w * dinv[c];
    atomicAdd(&agg[(size_t)r * D + f], h[(size_t)c * D + f] * nv);
}

// ---------------- finish: add self-loop term + bias (+relu), in place ----------------

template<int D, bool RELU>
__global__ void finish_k(float* __restrict__ agg, const float* __restrict__ h,
                         const float* __restrict__ dinv, const float* __restrict__ b, int n) {
    long long gid = (long long)blockIdx.x * blockDim.x + threadIdx.x;
    if (gid >= (long long)n * D) return;
    int i = (int)(gid / D), f = (int)(gid - (long long)i * D);
    float di = dinv[i];
    float v = agg[gid] + h[gid] * di * di + b[f];
    if (RELU) v = fmaxf(v, 0.0f);
    agg[gid] = v;
}

// ---------------- attention fusion + log_softmax: thread per node ----------------

__global__ __launch_bounds__(256) void fusion_k(const float* __restrict__ y1,
                                                const float* __restrict__ y2,
                                                const float* __restrict__ W1,
                                                const float* __restrict__ b1,
                                                const float* __restrict__ W2,
                                                float* __restrict__ out, int n) {
    __shared__ float W1s[40 * 40];
    __shared__ float b1s[40];
    __shared__ float W2s[40];
    int tid = threadIdx.x;
    for (int i = tid; i < 1600; i += 256) W1s[i] = W1[i];
    if (tid < 40) { b1s[tid] = b1[tid]; W2s[tid] = W2[tid]; }
    __syncthreads();
    int i = blockIdx.x * 256 + tid;
    if (i >= n) return;
    float z1[40], z2[40];
    const float4* y14 = reinterpret_cast<const float4*>(y1 + (size_t)i * 40);
    const float4* y24 = reinterpret_cast<const float4*>(y2 + (size_t)i * 40);
    #pragma unroll
    for (int q = 0; q < 10; q++) {
        float4 a = y14[q], b = y24[q];
        z1[4 * q] = a.x; z1[4 * q + 1] = a.y; z1[4 * q + 2] = a.z; z1[4 * q + 3] = a.w;
        z2[4 * q] = b.x; z2[4 * q + 1] = b.y; z2[4 * q + 2] = b.z; z2[4 * q + 3] = b.w;
    }
    float w1 = 0.f, w2 = 0.f;
    for (int c = 0; c < 40; c++) {
        float s1 = b1s[c], s2 = b1s[c];
        for (int j = 0; j < 40; j++) {
            float ww = W1s[j * 40 + c];
            s1 += z1[j] * ww; s2 += z2[j] * ww;
        }
        float wa = W2s[c];
        w1 += tanhf(s1) * wa; w2 += tanhf(s2) * wa;
    }
    float m = fmaxf(w1, w2);
    float e1 = expf(w1 - m), e2 = expf(w2 - m);
    float inv = 1.0f / (e1 + e2);
    float be1 = e1 * inv, be2 = e2 * inv;
    float fu[40];
    float mx = -1e30f;
    #pragma unroll
    for (int c = 0; c < 40; c++) {
        fu[c] = be1 * z1[c] + be2 * z2[c];
        mx = fmaxf(mx, fu[c]);
    }
    float se = 0.f;
    #pragma unroll
    for (int c = 0; c < 40; c++) se += expf(fu[c] - mx);
    float ls = logf(se);
    float4* o4 = reinterpret_cast<float4*>(out + (size_t)i * 40);
    #pragma unroll
    for (int q = 0; q < 10; q++) {
        float4 v;
        v.x = fu[4 * q] - mx - ls; v.y = fu[4 * q + 1] - mx - ls;
        v.z = fu[4 * q + 2] - mx - ls; v.w = fu[4 * q + 3] - mx - ls;
        o4[q] = v;
    }
}

// ---------------- host ----------------

extern "C" void kernel_launch(void* const* d_in, const int* in_sizes, int n_in,
                              void* d_out, int out_size, void* d_ws, size_t ws_size,
                              hipStream_t stream) {
    (void)in_sizes; (void)n_in; (void)out_size; (void)ws_size;
    const float* x   = (const float*)d_in[0];
    const float* Wg1 = (const float*)d_in[1];
    const float* bg1 = (const float*)d_in[2];
    const float* Wg2 = (const float*)d_in[3];
    const float* bg2 = (const float*)d_in[4];
    const float* Wa1 = (const float*)d_in[5];
    const float* ba1 = (const float*)d_in[6];
    const float* Wa2 = (const float*)d_in[7];
    const int* ei1 = (const int*)d_in[8];
    const int* ei2 = (const int*)d_in[9];
    const int *r1 = ei1, *c1 = ei1 + EE;
    const int *r2 = ei2, *c2 = ei2 + EE;
    float* out = (float*)d_out;

    float* ws = (float*)d_ws;
    float* norms1 = ws;  ws += NN;
    float* norms2 = ws;  ws += NN;
    float* deg    = ws;  ws += 2 * NN;          // deg1 | deg2 (later dinv)
    float* ew1    = ws;  ws += EE;
    float* ew2    = ws;  ws += EE;
    float* h      = ws;  ws += (size_t)NN * 128;
    float* agg1   = ws;  ws += (size_t)NN * 128; // -> x1
    float* agg2   = ws;  ws += (size_t)NN * 128; // -> x2
    float* aggy1  = ws;  ws += (size_t)NN * 40;  // -> y1
    float* aggy2  = ws;  ws += (size_t)NN * 40;  // -> y2
    float* deg1 = deg; float* deg2 = deg + NN;
    float* h2a = h;                  // reuse h region (h dead after finish1)
    float* h2b = h + (size_t)NN * 40;

    // zero accumulators (agg1+agg2 contiguous, aggy1+aggy2 contiguous)
    (void)hipMemsetAsync(agg1, 0, sizeof(float) * (size_t)NN * 256, stream);
    (void)hipMemsetAsync(aggy1, 0, sizeof(float) * (size_t)NN * 80, stream);
    set_ones_k<<<(2 * NN + 255) / 256, 256, 0, stream>>>(deg, 2 * NN);

    // ---- layer 1 ----
    row_norm_k<<<(NN + 3) / 4, 256, 0, stream>>>(x, norms1, NN);
    edge_sim_k<false><<<EE / 4, 256, 0, stream>>>(x, norms1, r1, c1, ew1, deg1, EE);
    edge_sim_k<false><<<EE / 4, 256, 0, stream>>>(x, norms1, r2, c2, ew2, deg2, EE);
    rsqrt_k<<<(2 * NN + 255) / 256, 256, 0, stream>>>(deg, 2 * NN);
    gemm_nh_k<<<(NN + 31) / 32, 256, 0, stream>>>(x, Wg1, h, NN);
    aggregate_k<128><<<(EE * 128) / 256, 256, 0, stream>>>(h, r1, c1, ew1, deg1, agg1, EE);
    aggregate_k<128><<<(EE * 128) / 256, 256, 0, stream>>>(h, r2, c2, ew2, deg2, agg2, EE);
    finish_k<128, true><<<((size_t)NN * 128 + 255) / 256, 256, 0, stream>>>(agg1, h, deg1, bg1, NN);
    finish_k<128, true><<<((size_t)NN * 128 + 255) / 256, 256, 0, stream>>>(agg2, h, deg2, bg1, NN);

    // ---- layer 2 ----
    set_ones_k<<<(2 * NN + 255) / 256, 256, 0, stream>>>(deg, 2 * NN);
    row_norm_k<<<(NN + 3) / 4, 256, 0, stream>>>(agg1, norms1, NN);
    row_norm_k<<<(NN + 3) / 4, 256, 0, stream>>>(agg2, norms2, NN);
    edge_sim_k<true><<<EE / 4, 256, 0, stream>>>(agg1, norms1, r1, c1, ew1, deg1, EE);
    edge_sim_k<true><<<EE / 4, 256, 0, stream>>>(agg2, norms2, r2, c2, ew2, deg2, EE);
    rsqrt_k<<<(2 * NN + 255) / 256, 256, 0, stream>>>(deg, 2 * NN);
    gemm_nc_k<<<(NN + 63) / 64, 256, 0, stream>>>(agg1, Wg2, h2a, NN);
    gemm_nc_k<<<(NN + 63) / 64, 256, 0, stream>>>(agg2, Wg2, h2b, NN);
    aggregate_k<40><<<(EE * 40) / 256, 256, 0, stream>>>(h2a, r1, c1, ew1, deg1, aggy1, EE);
    aggregate_k<40><<<(EE * 40) / 256, 256, 0, stream>>>(h2b, r2, c2, ew2, deg2, aggy2, EE);
    finish_k<40, false><<<((size_t)NN * 40 + 255) / 256, 256, 0, stream>>>(aggy1, h2a, deg1, bg2, NN);
    finish_k<40, false><<<((size_t)NN * 40 + 255) / 256, 256, 0, stream>>>(aggy2, h2b, deg2, bg2, NN);

    // ---- fusion + log_softmax ----
    fusion_k<<<(NN + 255) / 256, 256, 0, stream>>>(aggy1, aggy2, Wa1, ba1, Wa2, out, NN);
}

// Round 3
// 893.062 us; speedup vs baseline: 1.2891x; 1.2891x over previous
//
#include <hip/hip_runtime.h>
#include <hip/hip_bf16.h>

#define NN 100000
#define EE 800000
#define THRV 0.1f
#define DELTA 0.008f
#define EPSV 1e-8f

#define ATOMIC_ADD_F32 unsafeAtomicAdd

__device__ inline unsigned short f2bf(float f) {
    unsigned int u = __float_as_uint(f);
    u += 0x7fffu + ((u >> 16) & 1u);
    return (unsigned short)(u >> 16);
}

__device__ inline void unpack2(unsigned int u, float& lo, float& hi) {
    lo = __uint_as_float(u << 16);
    hi = __uint_as_float(u & 0xffff0000u);
}

// ---------------- utility ----------------

__global__ void rsqrt_k(float* __restrict__ p, int n) {
    int i = blockIdx.x * blockDim.x + threadIdx.x;
    if (i < n) p[i] = rsqrtf(p[i]);
}

// ---------------- normalize x -> bf16 rows + norms + deg=1 init ----------------
// one wave per node (4 per block)

__global__ __launch_bounds__(256) void normalize_k(const float* __restrict__ x,
                                                   unsigned short* __restrict__ xnb,
                                                   float* __restrict__ norms,
                                                   float* __restrict__ deg, int n) {
    int node = blockIdx.x * 4 + (threadIdx.x >> 6);
    int lane = threadIdx.x & 63;
    if (node >= n) return;
    float2 v = reinterpret_cast<const float2*>(x)[(size_t)node * 64 + lane];
    float ss = v.x * v.x + v.y * v.y;
    #pragma unroll
    for (int off = 32; off; off >>= 1) ss += __shfl_xor(ss, off);
    float norm = fmaxf(sqrtf(ss), EPSV);
    float inv = 1.0f / norm;
    ushort2 o;
    o.x = f2bf(v.x * inv);
    o.y = f2bf(v.y * inv);
    reinterpret_cast<ushort2*>(xnb)[(size_t)node * 64 + lane] = o;
    if (lane == 0) {
        norms[node] = norm;
        deg[node] = 1.0f;
        deg[node + NN] = 1.0f;
    }
}

// ---------------- first-pass edge sim: bf16 gather, 2 edges/wave, f32 fallback ----
// both edge sets in one launch; nb = blocks per set (EE/8)

__global__ __launch_bounds__(256) void edge_sim_bf_k(
        const unsigned short* __restrict__ xnb, const float* __restrict__ x,
        const float* __restrict__ norms,
        const int* __restrict__ r1, const int* __restrict__ c1,
        float* __restrict__ ew1, float* __restrict__ deg1,
        const int* __restrict__ r2, const int* __restrict__ c2,
        float* __restrict__ ew2, float* __restrict__ deg2, int nb) {
    int b = blockIdx.x;
    const int* rows; const int* cols; float* ew; float* deg;
    if (b < nb) { rows = r1; cols = c1; ew = ew1; deg = deg1; }
    else { b -= nb; rows = r2; cols = c2; ew = ew2; deg = deg2; }
    int tid = threadIdx.x;
    int lane = tid & 63;
    int e = b * 8 + ((tid >> 6) << 1) + (lane >> 5);   // 2 edges per wave
    int role = (lane >> 4) & 1;                        // 0: row endpoint, 1: col endpoint
    int l16 = lane & 15;
    int node = role ? cols[e] : rows[e];
    uint4 v = *reinterpret_cast<const uint4*>(xnb + (size_t)node * 128 + l16 * 8);
    uint4 p;
    p.x = (unsigned)__shfl_xor((int)v.x, 16);
    p.y = (unsigned)__shfl_xor((int)v.y, 16);
    p.z = (unsigned)__shfl_xor((int)v.z, 16);
    p.w = (unsigned)__shfl_xor((int)v.w, 16);
    float s = 0.f, lv, hv, lp, hp;
    unpack2(v.x, lv, hv); unpack2(p.x, lp, hp); s += lv * lp + hv * hp;
    unpack2(v.y, lv, hv); unpack2(p.y, lp, hp); s += lv * lp + hv * hp;
    unpack2(v.z, lv, hv); unpack2(p.z, lp, hp); s += lv * lp + hv * hp;
    unpack2(v.w, lv, hv); unpack2(p.w, lp, hp); s += lv * lp + hv * hp;
    #pragma unroll
    for (int off = 1; off < 16; off <<= 1) s += __shfl_xor(s, off);
    float sim = s;   // inputs pre-normalized -> dot == cosine sim
    if (fabsf(sim - THRV) <= DELTA) {
        // exact f32 recompute across the 32 lanes of this edge
        int r = rows[e], cc = cols[e];
        int j = lane & 31;
        const float2* xr = reinterpret_cast<const float2*>(x) + (size_t)r * 64;
        const float2* xc = reinterpret_cast<const float2*>(x) + (size_t)cc * 64;
        float2 a0 = xr[j], a1 = xr[j + 32];
        float2 b0 = xc[j], b1 = xc[j + 32];
        float d = a0.x * b0.x + a0.y * b0.y + a1.x * b1.x + a1.y * b1.y;
        #pragma unroll
        for (int off = 1; off < 32; off <<= 1) d += __shfl_xor(d, off);
        sim = d / (norms[r] * norms[cc]);
    }
    float w = (sim >= THRV) ? sim : 0.0f;
    if ((lane & 31) == 0) {
        ew[e] = w;
        if (w != 0.0f) ATOMIC_ADD_F32(&deg[rows[e]], w);
    }
}

// ---------------- second-pass edge sim: f32, alive-only, both sets ----------------
// nb = blocks per set (EE/4); one wave per edge

__global__ __launch_bounds__(256) void edge_sim2_k(
        const float* __restrict__ f1, const float* __restrict__ n1,
        const int* __restrict__ r1, const int* __restrict__ c1,
        float* __restrict__ ew1, float* __restrict__ deg1,
        const float* __restrict__ f2, const float* __restrict__ n2,
        const int* __restrict__ r2, const int* __restrict__ c2,
        float* __restrict__ ew2, float* __restrict__ deg2, int nb) {
    int b = blockIdx.x;
    const float* feat; const float* norms;
    const int* rows; const int* cols; float* ew; float* deg;
    if (b < nb) { feat = f1; norms = n1; rows = r1; cols = c1; ew = ew1; deg = deg1; }
    else { b -= nb; feat = f2; norms = n2; rows = r2; cols = c2; ew = ew2; deg = deg2; }
    int e = b * 4 + (threadIdx.x >> 6);
    int lane = threadIdx.x & 63;
    if (ew[e] == 0.0f) return;
    int r = rows[e], c = cols[e];
    const float2* xr = reinterpret_cast<const float2*>(feat) + (size_t)r * 64;
    const float2* xc = reinterpret_cast<const float2*>(feat) + (size_t)c * 64;
    float2 a = xr[lane], bb = xc[lane];
    float d = a.x * bb.x + a.y * bb.y;
    #pragma unroll
    for (int off = 32; off; off >>= 1) d += __shfl_xor(d, off);
    if (lane == 0) {
        float sim = d / (norms[r] * norms[c]);
        float w = (sim >= THRV) ? sim : 0.0f;
        ew[e] = w;
        if (w != 0.0f) ATOMIC_ADD_F32(&deg[r], w);
    }
}

// ---------------- layer-2 row norms over agg1|agg2 (2NN rows) + deg=1 ----------------

__global__ __launch_bounds__(256) void row_norm2_k(const float* __restrict__ xs,
                                                   float* __restrict__ norms,
                                                   float* __restrict__ deg, int n2) {
    int node = blockIdx.x * 4 + (threadIdx.x >> 6);
    int lane = threadIdx.x & 63;
    if (node >= n2) return;
    float2 v = reinterpret_cast<const float2*>(xs)[(size_t)node * 64 + lane];
    float ss = v.x * v.x + v.y * v.y;
    #pragma unroll
    for (int off = 32; off; off >>= 1) ss += __shfl_xor(ss, off);
    if (lane == 0) {
        norms[node] = fmaxf(sqrtf(ss), EPSV);
        deg[node] = 1.0f;
    }
}

// ---------------- GEMM: [n,128] x [128,128] -> [n,128] ----------------

__global__ __launch_bounds__(256) void gemm_nh_k(const float* __restrict__ A,
                                                 const float* __restrict__ W,
                                                 float* __restrict__ C, int n) {
    __shared__ float Ws[64 * 128];
    __shared__ float Xs[32 * 64];
    int tid = threadIdx.x;
    int row0 = blockIdx.x * 32;
    int cg = tid & 31;
    int rl = tid >> 5;
    float4 acc[4];
    #pragma unroll
    for (int i = 0; i < 4; i++) acc[i] = make_float4(0.f, 0.f, 0.f, 0.f);

    for (int kt = 0; kt < 2; kt++) {
        const float4* Wg = reinterpret_cast<const float4*>(W + kt * 64 * 128);
        float4* Ws4 = reinterpret_cast<float4*>(Ws);
        #pragma unroll
        for (int i = 0; i < 8; i++) Ws4[tid + 256 * i] = Wg[tid + 256 * i];
        float4* Xs4 = reinterpret_cast<float4*>(Xs);
        #pragma unroll
        for (int i = 0; i < 2; i++) {
            int idx = tid + 256 * i;
            int rr = idx >> 4, kq = idx & 15;
            int grow = row0 + rr; if (grow >= n) grow = n - 1;
            Xs4[idx] = reinterpret_cast<const float4*>(A + (size_t)grow * 128 + kt * 64)[kq];
        }
        __syncthreads();
        for (int k = 0; k < 64; k++) {
            float4 wv = reinterpret_cast<const float4*>(Ws + k * 128)[cg];
            #pragma unroll
            for (int r4 = 0; r4 < 4; r4++) {
                float xv = Xs[(rl + 8 * r4) * 64 + k];
                acc[r4].x += xv * wv.x; acc[r4].y += xv * wv.y;
                acc[r4].z += xv * wv.z; acc[r4].w += xv * wv.w;
            }
        }
        __syncthreads();
    }
    #pragma unroll
    for (int r4 = 0; r4 < 4; r4++) {
        int grow = row0 + rl + 8 * r4;
        if (grow < n) reinterpret_cast<float4*>(C + (size_t)grow * 128)[cg] = acc[r4];
    }
}

// ---------------- GEMM: [n,128] x [128,40] -> [n,40] ----------------

__global__ __launch_bounds__(256) void gemm_nc_k(const float* __restrict__ A,
                                                 const float* __restrict__ W,
                                                 float* __restrict__ C, int n) {
    __shared__ float Ws[128 * 40];
    __shared__ float Xs[64 * 130];
    int tid = threadIdx.x;
    int row0 = blockIdx.x * 64;
    for (int i = tid; i < 128 * 40; i += 256) Ws[i] = W[i];
    #pragma unroll
    for (int i = 0; i < 8; i++) {
        int idx = tid + 256 * i;
        int rr = idx >> 5, kq = idx & 31;
        int grow = row0 + rr; if (grow >= n) grow = n - 1;
        float4 v = reinterpret_cast<const float4*>(A + (size_t)grow * 128)[kq];
        float* dst = &Xs[rr * 130 + kq * 4];
        dst[0] = v.x; dst[1] = v.y; dst[2] = v.z; dst[3] = v.w;
    }
    __syncthreads();
    int c5 = tid & 7;
    int r  = tid >> 3;
    float acc0[5] = {0, 0, 0, 0, 0}, acc1[5] = {0, 0, 0, 0, 0};
    for (int k = 0; k < 128; k++) {
        float x0 = Xs[r * 130 + k], x1 = Xs[(r + 32) * 130 + k];
        #pragma unroll
        for (int c = 0; c < 5; c++) {
            float wv = Ws[k * 40 + c5 * 5 + c];
            acc0[c] += x0 * wv; acc1[c] += x1 * wv;
        }
    }
    int g0 = row0 + r, g1 = row0 + r + 32;
    if (g0 < n) {
        for (int c = 0; c < 5; c++) C[(size_t)g0 * 40 + c5 * 5 + c] = acc0[c];
    }
    if (g1 < n) {
        for (int c = 0; c < 5; c++) C[(size_t)g1 * 40 + c5 * 5 + c] = acc1[c];
    }
}

// ---------------- aggregate D=128: wave per edge, both sets ----------------
// nb = blocks per set (EE/4)

__global__ __launch_bounds__(256) void aggregate128_k(
        const float* __restrict__ h,
        const int* __restrict__ r1, const int* __restrict__ c1,
        const float* __restrict__ ew1, const float* __restrict__ dinv1,
        float* __restrict__ agg1,
        const int* __restrict__ r2, const int* __restrict__ c2,
        const float* __restrict__ ew2, const float* __restrict__ dinv2,
        float* __restrict__ agg2, int nb) {
    int b = blockIdx.x;
    const int* rows; const int* cols; const float* ew; const float* dinv; float* agg;
    if (b < nb) { rows = r1; cols = c1; ew = ew1; dinv = dinv1; agg = agg1; }
    else { b -= nb; rows = r2; cols = c2; ew = ew2; dinv = dinv2; agg = agg2; }
    int e = b * 4 + (threadIdx.x >> 6);
    int lane = threadIdx.x & 63;
    float w = ew[e];
    if (w == 0.0f) return;
    int r = rows[e], c = cols[e];
    float nv = dinv[r] * w * dinv[c];
    float2 hv = reinterpret_cast<const float2*>(h)[(size_t)c * 64 + lane];
    float* dst = agg + (size_t)r * 128 + lane * 2;
    ATOMIC_ADD_F32(dst, hv.x * nv);
    ATOMIC_ADD_F32(dst + 1, hv.y * nv);
}

// ---------------- aggregate D=40: thread per (edge,feature), both sets ----------------
// nb = blocks per set (EE*40/256)

__global__ __launch_bounds__(256) void aggregate40_k(
        const float* __restrict__ h2a,
        const int* __restrict__ r1, const int* __restrict__ c1,
        const float* __restrict__ ew1, const float* __restrict__ dinv1,
        float* __restrict__ aggy1,
        const float* __restrict__ h2b,
        const int* __restrict__ r2, const int* __restrict__ c2,
        const float* __restrict__ ew2, const float* __restrict__ dinv2,
        float* __restrict__ aggy2, int nb) {
    int b = blockIdx.x;
    const float* h2; const int* rows; const int* cols;
    const float* ew; const float* dinv; float* aggy;
    if (b < nb) { h2 = h2a; rows = r1; cols = c1; ew = ew1; dinv = dinv1; aggy = aggy1; }
    else { b -= nb; h2 = h2b; rows = r2; cols = c2; ew = ew2; dinv = dinv2; aggy = aggy2; }
    int gid = b * 256 + threadIdx.x;
    int e = gid / 40;
    int f = gid - e * 40;
    float w = ew[e];
    if (w == 0.0f) return;
    int r = rows[e], c = cols[e];
    float nv = dinv[r] * w * dinv[c];
    ATOMIC_ADD_F32(&aggy[(size_t)r * 40 + f], h2[(size_t)c * 40 + f] * nv);
}

// ---------------- finish (fused over both sets) ----------------

__global__ __launch_bounds__(256) void finish128_k(float* __restrict__ agg,
                                                   const float* __restrict__ h,
                                                   const float* __restrict__ dinv,
                                                   const float* __restrict__ b) {
    int gid = blockIdx.x * 256 + threadIdx.x;     // over 2*NN*128
    int i = gid >> 7;
    int f = gid & 127;
    const int nd = NN * 128;
    int hidx = (gid < nd) ? gid : gid - nd;
    float di = dinv[i];
    float v = agg[gid] + h[hidx] * di * di + b[f];
    agg[gid] = fmaxf(v, 0.0f);
}

__global__ __launch_bounds__(256) void finish40_k(float* __restrict__ aggy,
                                                  const float* __restrict__ h2,
                                                  const float* __restrict__ dinv,
                                                  const float* __restrict__ b) {
    int gid = blockIdx.x * 256 + threadIdx.x;     // over 2*NN*40
    int i = gid / 40;
    int f = gid - i * 40;
    float di = dinv[i];
    aggy[gid] = aggy[gid] + h2[gid] * di * di + b[f];
}

// ---------------- fusion + log_softmax ----------------

__global__ __launch_bounds__(256) void fusion_k(const float* __restrict__ y1,
                                                const float* __restrict__ y2,
                                                const float* __restrict__ W1,
                                                const float* __restrict__ b1,
                                                const float* __restrict__ W2,
                                                float* __restrict__ out, int n) {
    __shared__ float W1s[40 * 40];
    __shared__ float b1s[40];
    __shared__ float W2s[40];
    int tid = threadIdx.x;
    for (int i = tid; i < 1600; i += 256) W1s[i] = W1[i];
    if (tid < 40) { b1s[tid] = b1[tid]; W2s[tid] = W2[tid]; }
    __syncthreads();
    int i = blockIdx.x * 256 + tid;
    if (i >= n) return;
    float z1[40], z2[40];
    const float4* y14 = reinterpret_cast<const float4*>(y1 + (size_t)i * 40);
    const float4* y24 = reinterpret_cast<const float4*>(y2 + (size_t)i * 40);
    #pragma unroll
    for (int q = 0; q < 10; q++) {
        float4 a = y14[q], b = y24[q];
        z1[4 * q] = a.x; z1[4 * q + 1] = a.y; z1[4 * q + 2] = a.z; z1[4 * q + 3] = a.w;
        z2[4 * q] = b.x; z2[4 * q + 1] = b.y; z2[4 * q + 2] = b.z; z2[4 * q + 3] = b.w;
    }
    float w1 = 0.f, w2 = 0.f;
    for (int c = 0; c < 40; c++) {
        float s1 = b1s[c], s2 = b1s[c];
        for (int j = 0; j < 40; j++) {
            float ww = W1s[j * 40 + c];
            s1 += z1[j] * ww; s2 += z2[j] * ww;
        }
        float wa = W2s[c];
        w1 += tanhf(s1) * wa; w2 += tanhf(s2) * wa;
    }
    float m = fmaxf(w1, w2);
    float e1 = expf(w1 - m), e2 = expf(w2 - m);
    float inv = 1.0f / (e1 + e2);
    float be1 = e1 * inv, be2 = e2 * inv;
    float fu[40];
    float mx = -1e30f;
    #pragma unroll
    for (int c = 0; c < 40; c++) {
        fu[c] = be1 * z1[c] + be2 * z2[c];
        mx = fmaxf(mx, fu[c]);
    }
    float se = 0.f;
    #pragma unroll
    for (int c = 0; c < 40; c++) se += expf(fu[c] - mx);
    float ls = logf(se);
    float4* o4 = reinterpret_cast<float4*>(out + (size_t)i * 40);
    #pragma unroll
    for (int q = 0; q < 10; q++) {
        float4 v;
        v.x = fu[4 * q] - mx - ls; v.y = fu[4 * q + 1] - mx - ls;
        v.z = fu[4 * q + 2] - mx - ls; v.w = fu[4 * q + 3] - mx - ls;
        o4[q] = v;
    }
}

// ---------------- host ----------------

extern "C" void kernel_launch(void* const* d_in, const int* in_sizes, int n_in,
                              void* d_out, int out_size, void* d_ws, size_t ws_size,
                              hipStream_t stream) {
    (void)in_sizes; (void)n_in; (void)out_size; (void)ws_size;
    const float* x   = (const float*)d_in[0];
    const float* Wg1 = (const float*)d_in[1];
    const float* bg1 = (const float*)d_in[2];
    const float* Wg2 = (const float*)d_in[3];
    const float* bg2 = (const float*)d_in[4];
    const float* Wa1 = (const float*)d_in[5];
    const float* ba1 = (const float*)d_in[6];
    const float* Wa2 = (const float*)d_in[7];
    const int* ei1 = (const int*)d_in[8];
    const int* ei2 = (const int*)d_in[9];
    const int *r1 = ei1, *c1 = ei1 + EE;
    const int *r2 = ei2, *c2 = ei2 + EE;
    float* out = (float*)d_out;

    float* ws = (float*)d_ws;
    float* norms1 = ws;  ws += NN;
    float* norms2 = ws;  ws += NN;
    float* deg    = ws;  ws += 2 * NN;           // deg1 | deg2 (becomes dinv)
    float* ew1    = ws;  ws += EE;
    float* ew2    = ws;  ws += EE;
    float* h      = ws;  ws += (size_t)NN * 128;
    float* agg1   = ws;  ws += (size_t)NN * 128; // agg1 | agg2 contiguous
    float* agg2   = ws;  ws += (size_t)NN * 128;
    float* aggy1  = ws;  ws += (size_t)NN * 40;  // aggy1 | aggy2 contiguous
    float* aggy2  = ws;  ws += (size_t)NN * 40;
    float* deg1 = deg; float* deg2 = deg + NN;
    float* h2a = h;                              // h region reused (h2a | h2b contiguous)
    float* h2b = h + (size_t)NN * 40;
    unsigned short* xnb = (unsigned short*)aggy1; // overlays aggy (dead until L2 aggregate)

    // ---- layer 1 ----
    (void)hipMemsetAsync(agg1, 0, sizeof(float) * (size_t)NN * 256, stream);
    normalize_k<<<NN / 4, 256, 0, stream>>>(x, xnb, norms1, deg, NN);
    edge_sim_bf_k<<<2 * (EE / 8), 256, 0, stream>>>(xnb, x, norms1,
        r1, c1, ew1, deg1, r2, c2, ew2, deg2, EE / 8);
    // xnb dead from here; reclaim region for aggy
    (void)hipMemsetAsync(aggy1, 0, sizeof(float) * (size_t)NN * 80, stream);
    rsqrt_k<<<(2 * NN + 255) / 256, 256, 0, stream>>>(deg, 2 * NN);
    gemm_nh_k<<<NN / 32, 256, 0, stream>>>(x, Wg1, h, NN);
    aggregate128_k<<<2 * (EE / 4), 256, 0, stream>>>(h,
        r1, c1, ew1, deg1, agg1, r2, c2, ew2, deg2, agg2, EE / 4);
    finish128_k<<<(2 * NN * 128) / 256, 256, 0, stream>>>(agg1, h, deg, bg1);

    // ---- layer 2 ----
    row_norm2_k<<<(2 * NN) / 4, 256, 0, stream>>>(agg1, norms1, deg, 2 * NN);
    edge_sim2_k<<<2 * (EE / 4), 256, 0, stream>>>(agg1, norms1, r1, c1, ew1, deg1,
                                                  agg2, norms2, r2, c2, ew2, deg2, EE / 4);
    rsqrt_k<<<(2 * NN + 255) / 256, 256, 0, stream>>>(deg, 2 * NN);
    gemm_nc_k<<<(2 * NN) / 64, 256, 0, stream>>>(agg1, Wg2, h2a, 2 * NN);
    aggregate40_k<<<2 * (EE * 40 / 256), 256, 0, stream>>>(
        h2a, r1, c1, ew1, deg1, aggy1, h2b, r2, c2, ew2, deg2, aggy2, EE * 40 / 256);
    finish40_k<<<(2 * NN * 40) / 256, 256, 0, stream>>>(aggy1, h2a, deg, bg2);

    // ---- fusion + log_softmax ----
    fusion_k<<<(NN + 255) / 256, 256, 0, stream>>>(aggy1, aggy2, Wa1, ba1, Wa2, out, NN);
}